// Round 15
// baseline (225.750 us; speedup 1.0000x reference)
//
#include <hip/hip_runtime.h>

typedef __bf16 bf16x8_t __attribute__((ext_vector_type(8)));
typedef float f32x4_t __attribute__((ext_vector_type(4)));
typedef short s16x4 __attribute__((ext_vector_type(4)));
typedef unsigned short u16;
typedef unsigned int u32;
typedef unsigned long long u64;

__device__ __forceinline__ u16 f2b(float f) {
  __bf16 h = (__bf16)f;
  u16 u;
  __builtin_memcpy(&u, &h, 2);
  return u;
}
__device__ __forceinline__ float u2f(u32 u) {
  float f;
  __builtin_memcpy(&f, &u, 4);
  return f;
}

union FragU { u32 u[4]; bf16x8_t v; };
union PkU { u32 u[2]; s16x4 v; };

// ---------------- merged prep (one launch): maskbits | bias gather | weight cvt ----------------
__global__ void prep_all_k(const float* __restrict__ mask, u64* __restrict__ mbits,
                           const float* __restrict__ bias_table,
                           const int* __restrict__ rel_index, u16* __restrict__ bias_bf,
                           const float* __restrict__ qkv_w, const float* __restrict__ proj_w,
                           u16* __restrict__ wq, u16* __restrict__ wp) {
  const int bid = blockIdx.x;
  if (bid < 5488) {
    int row = bid * 4 + (threadIdx.x >> 6);  // 0..21951
    int lane = threadIdx.x & 63;
    const float* mrow = mask + (size_t)row * 343;
#pragma unroll
    for (int it = 0; it < 6; ++it) {
      int idx = it * 64 + lane;
      float v = (idx < 343) ? mrow[idx] : -100.0f;  // pad cols masked
      u64 b = __ballot(v < -50.0f);
      if (lane == 0) mbits[(size_t)row * 6 + it] = b;
    }
  } else if (bid < 8318) {
    int i = (bid - 5488) * 256 + threadIdx.x;
    if (i >= 6 * 343 * 352) return;
    int h = i / (343 * 352);
    int rem = i - h * (343 * 352);
    int r = rem / 352;
    int c = rem - r * 352;
    u16 val = 0;
    if (c < 343) {
      int idx = rel_index[r * 343 + c];
      val = f2b(bias_table[idx * 6 + h] * 1.4426950408889634f);
    }
    bias_bf[((size_t)h * 343 + r) * 352 + c] = val;
  } else {
    int i = (bid - 8318) * 256 + threadIdx.x;
    if (i < 110592) wq[i] = f2b(qkv_w[i]);
    int j = i - 110592;
    if (j >= 0 && j < 36864) wp[j] = f2b(proj_w[j]);
  }
}

// ---------------- QKV GEMM: [87808,192] x [576,192]^T -> q,k,v bf16 [b,h,n,32] ----------------
// R14 lesson: V must stay in the packed [b,h,n,32] layout — pre-transposed global V
// turned the epilogue into 704B-stride scatter (qkv 100us, WRITE-transaction bound).
// R14 counters (VALUBusy 14%, MfmaUtil 7%) show the cseg loop is inter-barrier
// stall-bound: w-load latency was exposed between barriers. T14 async-stage split:
// prefetch next cseg's w into REGISTERS during MFMA+epilogue, ds_write after barrier.
__global__ __launch_bounds__(256) void qkv_gemm(const float* __restrict__ x,
                                                const u16* __restrict__ w_bf,
                                                const float* __restrict__ qkv_b,
                                                u16* __restrict__ qb,
                                                u16* __restrict__ kb,
                                                u16* __restrict__ vb) {
  __shared__ u16 xs[64][200];   // +8 pad
  __shared__ u16 wsx[64][200];
  const int m0 = blockIdx.x * 64;
  const float* xrow = x + (size_t)m0 * 192;
#pragma unroll
  for (int i = 0; i < 12; ++i) {
    int idx = threadIdx.x + 256 * i;
    float4 f = ((const float4*)xrow)[idx];
    int r = idx / 48, k4 = (idx % 48) * 4;
    ushort4 a;
    a.x = f2b(f.x); a.y = f2b(f.y); a.z = f2b(f.z); a.w = f2b(f.w);
    *(ushort4*)&xs[r][k4] = a;
  }
  const int lane = threadIdx.x & 63;
  const int wv = threadIdx.x >> 6;
  const int wm = wv >> 1, wn = wv & 1;
  const int lr = lane & 15, g = lane >> 4;
  // hoisted per-row offsets (gr independent of cseg): 8 divs/thread instead of 144
  int rowoff[2][4];
#pragma unroll
  for (int mt = 0; mt < 2; ++mt)
#pragma unroll
    for (int r = 0; r < 4; ++r) {
      int gr = m0 + wm * 32 + mt * 16 + g * 4 + r;
      int b_ = gr / 343;
      int n = gr - b_ * 343;
      rowoff[mt][r] = (b_ * 2058 + n) * 32;
    }
  // stage w[0] (regs -> LDS), single barrier covers x too
  float4 wreg[6];
#pragma unroll
  for (int i = 0; i < 6; ++i)
    wreg[i] = ((const float4*)w_bf)[threadIdx.x + 256 * i];
#pragma unroll
  for (int i = 0; i < 6; ++i) {
    int idx = threadIdx.x + 256 * i;
    *(float4*)&wsx[idx / 24][(idx % 24) * 8] = wreg[i];
  }
  __syncthreads();
  const f32x4_t zro = {0.f, 0.f, 0.f, 0.f};
  for (int cseg = 0; cseg < 9; ++cseg) {
    // T14: issue next w-chunk loads now; latency hides under MFMA + epilogue
    if (cseg < 8) {
      const u16* wnext = w_bf + (size_t)(cseg + 1) * 64 * 192;
#pragma unroll
      for (int i = 0; i < 6; ++i)
        wreg[i] = ((const float4*)wnext)[threadIdx.x + 256 * i];
    }
    f32x4_t acc[2][2];
    acc[0][0] = zro; acc[0][1] = zro; acc[1][0] = zro; acc[1][1] = zro;
#pragma unroll
    for (int ks = 0; ks < 6; ++ks) {
      bf16x8_t af[2], bfr[2];
#pragma unroll
      for (int t2 = 0; t2 < 2; ++t2) {
        af[t2] = *(const bf16x8_t*)&xs[wm * 32 + t2 * 16 + lr][ks * 32 + g * 8];
        bfr[t2] = *(const bf16x8_t*)&wsx[wn * 32 + t2 * 16 + lr][ks * 32 + g * 8];
      }
#pragma unroll
      for (int mt = 0; mt < 2; ++mt)
#pragma unroll
        for (int nt = 0; nt < 2; ++nt)
          acc[mt][nt] = __builtin_amdgcn_mfma_f32_16x16x32_bf16(af[mt], bfr[nt], acc[mt][nt], 0, 0, 0);
    }
    const int c0 = cseg * 64;
    const int seg = c0 / 192;  // 0=q 1=k 2=v
    u16* dst = (seg == 0) ? qb : ((seg == 1) ? kb : vb);
    // q gets attention scale AND log2(e) folded in (exp2-based softmax downstream)
    const float scl = (seg == 0) ? (0.17677669529663687f * 1.4426950408889634f) : 1.0f;
#pragma unroll
    for (int mt = 0; mt < 2; ++mt) {
#pragma unroll
      for (int nt = 0; nt < 2; ++nt) {
        int gc = c0 + wn * 32 + nt * 16 + lr;
        float bias = qkv_b[gc];
        int c2 = gc - seg * 192;
        int hoff = (c2 >> 5) * 10976 + (c2 & 31);  // h*343*32 + d
#pragma unroll
        for (int r = 0; r < 4; ++r) {
          dst[(size_t)(rowoff[mt][r] + hoff)] = f2b((acc[mt][nt][r] + bias) * scl);
        }
      }
    }
    if (cseg < 8) {
      __syncthreads();  // all waves done reading wsx for this cseg
#pragma unroll
      for (int i = 0; i < 6; ++i) {
        int idx = threadIdx.x + 256 * i;
        *(float4*)&wsx[idx / 24][(idx % 24) * 8] = wreg[i];
      }
      __syncthreads();  // wsx ready for next cseg
    }
  }
}

// ---------------- fused attention: one block per (b,h), 8 waves x 3 row-tile passes ----------------
// R11 attn verbatim (best measured: 92.7-92.9us, FETCH 67MB). R13 refuted K-from-L2
// (125us); R14 refuted global V-pre-transpose (qkv scatter). K+V stay LDS-staged here.
// 512 thr / 8 waves, 3 blocks/CU (R6 lesson). launch_bounds(512,2) (R2/R12 lesson:
// never cap below measured VGPR need).
// Bias C-operand in regs from 8B bf16 loads (R7/R8 lesson); mask post-exp zeroing.
// PV uses mfma 16x16x16: B-frag layout matches where swapped-QK^T leaves P -> zero shuffles.
__global__ __launch_bounds__(512, 2) void attn_k(const u16* __restrict__ qg,
                                                 const u16* __restrict__ kg,
                                                 const u16* __restrict__ vg,
                                                 const u16* __restrict__ bias_bf,
                                                 const u64* __restrict__ mbits,
                                                 u16* __restrict__ ao) {
  __shared__ u16 ksm[352][40];   // K [kc][d], +8 pad; rows 343..351 zeroed
  __shared__ u16 vtm[32][372];   // V^T [d][kc], stride 372 -> 8B frag reads 2-way (free)
  const int bh = blockIdx.x;    // 0..1535
  const int b_ = bh / 6;
  const int h = bh - b_ * 6;
  const int w = b_ & 63;
  const int t = threadIdx.x;
  const int lane = t & 63;
  const int wv = t >> 6;
  const u16* kbh = kg + (size_t)bh * 10976;
  const u16* vbh = vg + (size_t)bh * 10976;
  // stage K (343 rows x 32 d), 4 float4 per row
  for (int i = t; i < 1372; i += 512) {
    float4 f = ((const float4*)kbh)[i];
    *(float4*)&ksm[i >> 2][(i & 3) * 8] = f;
  }
  if (t < 360) ksm[343 + t / 40][t % 40] = 0;  // zero K pad rows
  // stage V transposed: each lane owns a distinct column n -> write ~2-way
#pragma unroll
  for (int k = 0; k < 3; ++k) {
    int dq = t >> 7;                   // 0..3, uniform per wave-pair
    int n = k * 128 + (t & 127);
    if (n < 343) {
      union { float4 f4; u16 s[8]; } u;
      u.f4 = ((const float4*)vbh)[n * 4 + dq];
#pragma unroll
      for (int j = 0; j < 8; ++j) vtm[dq * 8 + j][n] = u.s[j];
    }
  }
  for (int i = t; i < 928; i += 512) vtm[i / 29][343 + i % 29] = 0;  // zero V pad cols
  __syncthreads();
  const int lr = lane & 15, g = lane >> 4;
  const f32x4_t zro = {0.f, 0.f, 0.f, 0.f};
  for (int pass = 0; pass < 3; ++pass) {
    const int rt = pass * 8 + wv;  // row-tile 0..21
    if (rt >= 22) break;
    const int q0 = rt * 16;
    const int qi = q0 + lr;
    const bool qv = qi < 343;
    const int qic = qv ? qi : 342;
    FragU qfu;
    qfu.u[0] = 0u; qfu.u[1] = 0u; qfu.u[2] = 0u; qfu.u[3] = 0u;
    if (qv) qfu.v = *(const bf16x8_t*)(qg + ((size_t)bh * 343 + qi) * 32 + g * 8);
    const u16* brow = bias_bf + ((size_t)h * 343 + qic) * 352;
    const u64* mrow = mbits + ((size_t)w * 343 + qic) * 6;
    u64 mw[6];
#pragma unroll
    for (int i2 = 0; i2 < 6; ++i2) mw[i2] = mrow[i2];
    // fused sweep: bias pair-load -> f32 C in regs -> MFMA(+bias) -> exp2 -> mask-zero -> pack
    float sum = 0.f;
    PkU pk[22];
#pragma unroll
    for (int ct = 0; ct < 22; ++ct) {
      int kjb = ct * 16 + 4 * g;
      union { uint2 u2; u32 w2[2]; } bv;
      bv.u2 = *(const uint2*)&brow[kjb];  // 8B: 4 bf16 bias values
      f32x4_t c4;
      c4[0] = u2f(bv.w2[0] << 16);
      c4[1] = u2f(bv.w2[0] & 0xFFFF0000u);
      c4[2] = u2f(bv.w2[1] << 16);
      c4[3] = u2f(bv.w2[1] & 0xFFFF0000u);
      bf16x8_t af = *(const bf16x8_t*)&ksm[ct * 16 + lr][g * 8];
      f32x4_t s4 = __builtin_amdgcn_mfma_f32_16x16x32_bf16(af, qfu.v, c4, 0, 0, 0);
      u32 bits4 = (u32)(mw[ct >> 2] >> ((ct & 3) * 16 + 4 * g)) & 0xFu;
      float p0 = ((bits4 >> 0) & 1u) ? 0.f : __builtin_amdgcn_exp2f(s4[0]);
      float p1 = ((bits4 >> 1) & 1u) ? 0.f : __builtin_amdgcn_exp2f(s4[1]);
      float p2 = ((bits4 >> 2) & 1u) ? 0.f : __builtin_amdgcn_exp2f(s4[2]);
      float p3 = ((bits4 >> 3) & 1u) ? 0.f : __builtin_amdgcn_exp2f(s4[3]);
      sum += (p0 + p1) + (p2 + p3);
      pk[ct].u[0] = (u32)f2b(p0) | ((u32)f2b(p1) << 16);
      pk[ct].u[1] = (u32)f2b(p2) | ((u32)f2b(p3) << 16);
    }
    sum += __shfl_xor(sum, 16, 64);
    sum += __shfl_xor(sum, 32, 64);
    const float inv = 1.0f / sum;
    // O^T = V^T · P^T via 16x16x16 MFMA; pk[ct] IS the B-fragment for k-tile ct.
    f32x4_t oa[2] = {zro, zro};
#pragma unroll
    for (int ct = 0; ct < 22; ++ct) {
      s16x4 bfrag = pk[ct].v;
#pragma unroll
      for (int mt = 0; mt < 2; ++mt) {
        s16x4 af = *(const s16x4*)&vtm[mt * 16 + lr][ct * 16 + g * 4];
        oa[mt] = __builtin_amdgcn_mfma_f32_16x16x16bf16_1k(af, bfrag, oa[mt], 0, 0, 0);
      }
    }
    if (qv) {
      u16* orow = ao + ((size_t)b_ * 343 + qi) * 192 + h * 32;
#pragma unroll
      for (int mt = 0; mt < 2; ++mt) {
        ushort4 sv;
        sv.x = f2b(oa[mt][0] * inv);
        sv.y = f2b(oa[mt][1] * inv);
        sv.z = f2b(oa[mt][2] * inv);
        sv.w = f2b(oa[mt][3] * inv);
        *(ushort4*)&orow[mt * 16 + 4 * g] = sv;
      }
    }
  }
}

// ---------------- proj GEMM: [87808,192] bf16 x [192,192]^T + b -> fp32 out ----------------
__global__ __launch_bounds__(256) void proj_gemm(const u16* __restrict__ ao,
                                                 const u16* __restrict__ wp_bf,
                                                 const float* __restrict__ proj_b,
                                                 float* __restrict__ out) {
  __shared__ u16 as_[64][200];
  __shared__ u16 wsx[64][200];
  const int m0 = blockIdx.x * 64;
  const u16* arow = ao + (size_t)m0 * 192;
#pragma unroll
  for (int i = 0; i < 6; ++i) {
    int idx = threadIdx.x + 256 * i;
    float4 f = ((const float4*)arow)[idx];
    *(float4*)&as_[idx / 24][(idx % 24) * 8] = f;
  }
  const int lane = threadIdx.x & 63;
  const int wv = threadIdx.x >> 6;
  const int wm = wv >> 1, wn = wv & 1;
  const int lr = lane & 15, g = lane >> 4;
  const f32x4_t zro = {0.f, 0.f, 0.f, 0.f};
  for (int cseg = 0; cseg < 3; ++cseg) {
    __syncthreads();
    const u16* wrow = wp_bf + (size_t)cseg * 64 * 192;
#pragma unroll
    for (int i = 0; i < 6; ++i) {
      int idx = threadIdx.x + 256 * i;
      float4 f = ((const float4*)wrow)[idx];
      *(float4*)&wsx[idx / 24][(idx % 24) * 8] = f;
    }
    __syncthreads();
    f32x4_t acc[2][2];
    acc[0][0] = zro; acc[0][1] = zro; acc[1][0] = zro; acc[1][1] = zro;
#pragma unroll
    for (int ks = 0; ks < 6; ++ks) {
      bf16x8_t af[2], bfr[2];
#pragma unroll
      for (int t2 = 0; t2 < 2; ++t2) {
        af[t2] = *(const bf16x8_t*)&as_[wm * 32 + t2 * 16 + lr][ks * 32 + g * 8];
        bfr[t2] = *(const bf16x8_t*)&wsx[wn * 32 + t2 * 16 + lr][ks * 32 + g * 8];
      }
#pragma unroll
      for (int mt = 0; mt < 2; ++mt)
#pragma unroll
        for (int nt = 0; nt < 2; ++nt)
          acc[mt][nt] = __builtin_amdgcn_mfma_f32_16x16x32_bf16(af[mt], bfr[nt], acc[mt][nt], 0, 0, 0);
    }
    const int c0 = cseg * 64;
#pragma unroll
    for (int mt = 0; mt < 2; ++mt) {
#pragma unroll
      for (int nt = 0; nt < 2; ++nt) {
        int gc = c0 + wn * 32 + nt * 16 + lr;
        float bias = proj_b[gc];
#pragma unroll
        for (int r = 0; r < 4; ++r) {
          int gr = m0 + wm * 32 + mt * 16 + g * 4 + r;
          out[(size_t)gr * 192 + gc] = acc[mt][nt][r] + bias;
        }
      }
    }
  }
}

extern "C" void kernel_launch(void* const* d_in, const int* in_sizes, int n_in,
                              void* d_out, int out_size, void* d_ws, size_t ws_size,
                              hipStream_t stream) {
  const float* x = (const float*)d_in[0];
  const float* mask = (const float*)d_in[1];
  const float* qkv_w = (const float*)d_in[2];
  const float* qkv_b = (const float*)d_in[3];
  const float* proj_w = (const float*)d_in[4];
  const float* proj_b = (const float*)d_in[5];
  const float* bias_table = (const float*)d_in[6];
  const int* rel_index = (const int*)d_in[7];
  float* out = (float*)d_out;
  char* ws = (char*)d_ws;

  // ws layout (bytes) — R11 layout restored
  u16* qb      = (u16*)(ws + 0);          // 33,718,272
  u16* kb      = (u16*)(ws + 33718272);   // 33,718,272
  u16* vb      = (u16*)(ws + 67436544);   // 33,718,272
  u16* ao      = (u16*)(ws + 101154816);  // 33,718,272
  u16* bias_bf = (u16*)(ws + 134873088);  // 1,449,216
  u64* mbits   = (u64*)(ws + 136322304);  // 1,053,696
  u16* wq_bf   = (u16*)(ws + 137376000);  // 221,184
  u16* wp_bf   = (u16*)(ws + 137597184);  // 73,728 -> end 137,670,912

  prep_all_k<<<8894, 256, 0, stream>>>(mask, mbits, bias_table, rel_index, bias_bf,
                                       qkv_w, proj_w, wq_bf, wp_bf);
  qkv_gemm<<<1372, 256, 0, stream>>>(x, wq_bf, qkv_b, qb, kb, vb);
  attn_k<<<1536, 512, 0, stream>>>(qb, kb, vb, bias_bf, mbits, ao);
  proj_gemm<<<1372, 256, 0, stream>>>(ao, wp_bf, proj_b, out);
}

// Round 16
// 167.933 us; speedup vs baseline: 1.3443x; 1.3443x over previous
//
#include <hip/hip_runtime.h>

typedef __bf16 bf16x8_t __attribute__((ext_vector_type(8)));
typedef float f32x4_t __attribute__((ext_vector_type(4)));
typedef short s16x4 __attribute__((ext_vector_type(4)));
typedef unsigned short u16;
typedef unsigned int u32;
typedef unsigned long long u64;

__device__ __forceinline__ u16 f2b(float f) {
  __bf16 h = (__bf16)f;
  u16 u;
  __builtin_memcpy(&u, &h, 2);
  return u;
}
__device__ __forceinline__ float u2f(u32 u) {
  float f;
  __builtin_memcpy(&f, &u, 4);
  return f;
}

union FragU { u32 u[4]; bf16x8_t v; };
union PkU { u32 u[2]; s16x4 v; };

// ============================ FINAL CONFIG (R11, 167.6us) ============================
// Twice-verified best (R9: 167.55, R11: 167.66). Escape attempts R10/R12-R15 all
// regressed and are documented inline as lessons:
//  R2/R12/R15: launch_bounds or allocator-refused register growth -> scratch spill
//              (watch VGPR_Count + WRITE_SIZE); never cap below measured need.
//  R6: bigger blocks lose the occupancy tier (2048-thread cap).
//  R7/R8: MFMA C-operand from global loads serializes/bursts; build C in regs from
//         small bf16 loads instead.
//  R10: linear [row][192] k/v layout half-uses 128B lines in attn staging (+54MB).
//  R13: K-from-L2 puts ~200cy loads on the MFMA critical path (TLP can't hide at
//       6 waves/SIMD) — K stays LDS-staged.
//  R14: global pre-transposed V = 704B-stride store scatter; transpose in LDS.
// =====================================================================================

// ---------------- merged prep (one launch): maskbits | bias gather | weight cvt ----------------
__global__ void prep_all_k(const float* __restrict__ mask, u64* __restrict__ mbits,
                           const float* __restrict__ bias_table,
                           const int* __restrict__ rel_index, u16* __restrict__ bias_bf,
                           const float* __restrict__ qkv_w, const float* __restrict__ proj_w,
                           u16* __restrict__ wq, u16* __restrict__ wp) {
  const int bid = blockIdx.x;
  if (bid < 5488) {
    int row = bid * 4 + (threadIdx.x >> 6);  // 0..21951
    int lane = threadIdx.x & 63;
    const float* mrow = mask + (size_t)row * 343;
#pragma unroll
    for (int it = 0; it < 6; ++it) {
      int idx = it * 64 + lane;
      float v = (idx < 343) ? mrow[idx] : -100.0f;  // pad cols masked
      u64 b = __ballot(v < -50.0f);
      if (lane == 0) mbits[(size_t)row * 6 + it] = b;
    }
  } else if (bid < 8318) {
    int i = (bid - 5488) * 256 + threadIdx.x;
    if (i >= 6 * 343 * 352) return;
    int h = i / (343 * 352);
    int rem = i - h * (343 * 352);
    int r = rem / 352;
    int c = rem - r * 352;
    u16 val = 0;
    if (c < 343) {
      int idx = rel_index[r * 343 + c];
      val = f2b(bias_table[idx * 6 + h] * 1.4426950408889634f);
    }
    bias_bf[((size_t)h * 343 + r) * 352 + c] = val;
  } else {
    int i = (bid - 8318) * 256 + threadIdx.x;
    if (i < 110592) wq[i] = f2b(qkv_w[i]);
    int j = i - 110592;
    if (j >= 0 && j < 36864) wp[j] = f2b(proj_w[j]);
  }
}

// ---------------- QKV GEMM: [87808,192] x [576,192]^T -> q,k,v bf16 [b,h,n,32] ----------------
__global__ __launch_bounds__(256) void qkv_gemm(const float* __restrict__ x,
                                                const u16* __restrict__ w_bf,
                                                const float* __restrict__ qkv_b,
                                                u16* __restrict__ qb,
                                                u16* __restrict__ kb,
                                                u16* __restrict__ vb) {
  __shared__ u16 xs[64][200];   // +8 pad
  __shared__ u16 wsx[64][200];
  const int m0 = blockIdx.x * 64;
  const float* xrow = x + (size_t)m0 * 192;
#pragma unroll
  for (int i = 0; i < 12; ++i) {
    int idx = threadIdx.x + 256 * i;
    float4 f = ((const float4*)xrow)[idx];
    int r = idx / 48, k4 = (idx % 48) * 4;
    ushort4 a;
    a.x = f2b(f.x); a.y = f2b(f.y); a.z = f2b(f.z); a.w = f2b(f.w);
    *(ushort4*)&xs[r][k4] = a;
  }
  const int lane = threadIdx.x & 63;
  const int wv = threadIdx.x >> 6;
  const int wm = wv >> 1, wn = wv & 1;
  const int lr = lane & 15, g = lane >> 4;
  // hoisted per-row offsets (gr independent of cseg): 8 divs/thread instead of 144
  int rowoff[2][4];
#pragma unroll
  for (int mt = 0; mt < 2; ++mt)
#pragma unroll
    for (int r = 0; r < 4; ++r) {
      int gr = m0 + wm * 32 + mt * 16 + g * 4 + r;
      int b_ = gr / 343;
      int n = gr - b_ * 343;
      rowoff[mt][r] = (b_ * 2058 + n) * 32;
    }
  const f32x4_t zro = {0.f, 0.f, 0.f, 0.f};
  for (int cseg = 0; cseg < 9; ++cseg) {
    __syncthreads();
    const u16* wrow = w_bf + (size_t)cseg * 64 * 192;
#pragma unroll
    for (int i = 0; i < 6; ++i) {
      int idx = threadIdx.x + 256 * i;  // 16B chunks
      float4 f = ((const float4*)wrow)[idx];
      *(float4*)&wsx[idx / 24][(idx % 24) * 8] = f;
    }
    __syncthreads();
    f32x4_t acc[2][2];
    acc[0][0] = zro; acc[0][1] = zro; acc[1][0] = zro; acc[1][1] = zro;
#pragma unroll
    for (int ks = 0; ks < 6; ++ks) {
      bf16x8_t af[2], bfr[2];
#pragma unroll
      for (int t2 = 0; t2 < 2; ++t2) {
        af[t2] = *(const bf16x8_t*)&xs[wm * 32 + t2 * 16 + lr][ks * 32 + g * 8];
        bfr[t2] = *(const bf16x8_t*)&wsx[wn * 32 + t2 * 16 + lr][ks * 32 + g * 8];
      }
#pragma unroll
      for (int mt = 0; mt < 2; ++mt)
#pragma unroll
        for (int nt = 0; nt < 2; ++nt)
          acc[mt][nt] = __builtin_amdgcn_mfma_f32_16x16x32_bf16(af[mt], bfr[nt], acc[mt][nt], 0, 0, 0);
    }
    const int c0 = cseg * 64;
    const int seg = c0 / 192;  // 0=q 1=k 2=v
    u16* dst = (seg == 0) ? qb : ((seg == 1) ? kb : vb);
    // q gets attention scale AND log2(e) folded in (exp2-based softmax downstream)
    const float scl = (seg == 0) ? (0.17677669529663687f * 1.4426950408889634f) : 1.0f;
#pragma unroll
    for (int mt = 0; mt < 2; ++mt) {
#pragma unroll
      for (int nt = 0; nt < 2; ++nt) {
        int gc = c0 + wn * 32 + nt * 16 + lr;
        float bias = qkv_b[gc];
        int c2 = gc - seg * 192;
        int hoff = (c2 >> 5) * 10976 + (c2 & 31);  // h*343*32 + d
#pragma unroll
        for (int r = 0; r < 4; ++r) {
          dst[(size_t)(rowoff[mt][r] + hoff)] = f2b((acc[mt][nt][r] + bias) * scl);
        }
      }
    }
  }
}

// ---------------- fused attention: one block per (b,h), 8 waves x 3 row-tile passes ----------------
// Best measured: 92.7-92.9us. 512 thr / 8 waves, 3 blocks/CU; launch_bounds(512,2).
// Single-sweep softmax (no max pass; logits O(1) by construction), exp2 with log2e
// prefolded into q/bias; bias C-operand built in regs from 8B bf16 pair loads;
// mask applied post-exp as zeroing (exact: masked exp(s-100) < 4e-44 == 0 in f32).
// PV uses mfma 16x16x16: B-frag layout matches where swapped-QK^T leaves P -> zero shuffles.
__global__ __launch_bounds__(512, 2) void attn_k(const u16* __restrict__ qg,
                                                 const u16* __restrict__ kg,
                                                 const u16* __restrict__ vg,
                                                 const u16* __restrict__ bias_bf,
                                                 const u64* __restrict__ mbits,
                                                 u16* __restrict__ ao) {
  __shared__ u16 ksm[352][40];   // K [kc][d], +8 pad; rows 343..351 zeroed
  __shared__ u16 vtm[32][372];   // V^T [d][kc], stride 372 -> 8B frag reads 2-way (free)
  const int bh = blockIdx.x;    // 0..1535
  const int b_ = bh / 6;
  const int h = bh - b_ * 6;
  const int w = b_ & 63;
  const int t = threadIdx.x;
  const int lane = t & 63;
  const int wv = t >> 6;
  const u16* kbh = kg + (size_t)bh * 10976;
  const u16* vbh = vg + (size_t)bh * 10976;
  // stage K (343 rows x 32 d), 4 float4 per row
  for (int i = t; i < 1372; i += 512) {
    float4 f = ((const float4*)kbh)[i];
    *(float4*)&ksm[i >> 2][(i & 3) * 8] = f;
  }
  if (t < 360) ksm[343 + t / 40][t % 40] = 0;  // zero K pad rows
  // stage V transposed: each lane owns a distinct column n -> write ~2-way
#pragma unroll
  for (int k = 0; k < 3; ++k) {
    int dq = t >> 7;                   // 0..3, uniform per wave-pair
    int n = k * 128 + (t & 127);
    if (n < 343) {
      union { float4 f4; u16 s[8]; } u;
      u.f4 = ((const float4*)vbh)[n * 4 + dq];
#pragma unroll
      for (int j = 0; j < 8; ++j) vtm[dq * 8 + j][n] = u.s[j];
    }
  }
  for (int i = t; i < 928; i += 512) vtm[i / 29][343 + i % 29] = 0;  // zero V pad cols
  __syncthreads();
  const int lr = lane & 15, g = lane >> 4;
  const f32x4_t zro = {0.f, 0.f, 0.f, 0.f};
  for (int pass = 0; pass < 3; ++pass) {
    const int rt = pass * 8 + wv;  // row-tile 0..21
    if (rt >= 22) break;
    const int q0 = rt * 16;
    const int qi = q0 + lr;
    const bool qv = qi < 343;
    const int qic = qv ? qi : 342;
    FragU qfu;
    qfu.u[0] = 0u; qfu.u[1] = 0u; qfu.u[2] = 0u; qfu.u[3] = 0u;
    if (qv) qfu.v = *(const bf16x8_t*)(qg + ((size_t)bh * 343 + qi) * 32 + g * 8);
    const u16* brow = bias_bf + ((size_t)h * 343 + qic) * 352;
    const u64* mrow = mbits + ((size_t)w * 343 + qic) * 6;
    u64 mw[6];
#pragma unroll
    for (int i2 = 0; i2 < 6; ++i2) mw[i2] = mrow[i2];
    // fused sweep: bias pair-load -> f32 C in regs -> MFMA(+bias) -> exp2 -> mask-zero -> pack
    float sum = 0.f;
    PkU pk[22];
#pragma unroll
    for (int ct = 0; ct < 22; ++ct) {
      int kjb = ct * 16 + 4 * g;
      union { uint2 u2; u32 w2[2]; } bv;
      bv.u2 = *(const uint2*)&brow[kjb];  // 8B: 4 bf16 bias values
      f32x4_t c4;
      c4[0] = u2f(bv.w2[0] << 16);
      c4[1] = u2f(bv.w2[0] & 0xFFFF0000u);
      c4[2] = u2f(bv.w2[1] << 16);
      c4[3] = u2f(bv.w2[1] & 0xFFFF0000u);
      bf16x8_t af = *(const bf16x8_t*)&ksm[ct * 16 + lr][g * 8];
      f32x4_t s4 = __builtin_amdgcn_mfma_f32_16x16x32_bf16(af, qfu.v, c4, 0, 0, 0);
      u32 bits4 = (u32)(mw[ct >> 2] >> ((ct & 3) * 16 + 4 * g)) & 0xFu;
      float p0 = ((bits4 >> 0) & 1u) ? 0.f : __builtin_amdgcn_exp2f(s4[0]);
      float p1 = ((bits4 >> 1) & 1u) ? 0.f : __builtin_amdgcn_exp2f(s4[1]);
      float p2 = ((bits4 >> 2) & 1u) ? 0.f : __builtin_amdgcn_exp2f(s4[2]);
      float p3 = ((bits4 >> 3) & 1u) ? 0.f : __builtin_amdgcn_exp2f(s4[3]);
      sum += (p0 + p1) + (p2 + p3);
      pk[ct].u[0] = (u32)f2b(p0) | ((u32)f2b(p1) << 16);
      pk[ct].u[1] = (u32)f2b(p2) | ((u32)f2b(p3) << 16);
    }
    sum += __shfl_xor(sum, 16, 64);
    sum += __shfl_xor(sum, 32, 64);
    const float inv = 1.0f / sum;
    // O^T = V^T · P^T via 16x16x16 MFMA; pk[ct] IS the B-fragment for k-tile ct.
    f32x4_t oa[2] = {zro, zro};
#pragma unroll
    for (int ct = 0; ct < 22; ++ct) {
      s16x4 bfrag = pk[ct].v;
#pragma unroll
      for (int mt = 0; mt < 2; ++mt) {
        s16x4 af = *(const s16x4*)&vtm[mt * 16 + lr][ct * 16 + g * 4];
        oa[mt] = __builtin_amdgcn_mfma_f32_16x16x16bf16_1k(af, bfrag, oa[mt], 0, 0, 0);
      }
    }
    if (qv) {
      u16* orow = ao + ((size_t)b_ * 343 + qi) * 192 + h * 32;
#pragma unroll
      for (int mt = 0; mt < 2; ++mt) {
        ushort4 sv;
        sv.x = f2b(oa[mt][0] * inv);
        sv.y = f2b(oa[mt][1] * inv);
        sv.z = f2b(oa[mt][2] * inv);
        sv.w = f2b(oa[mt][3] * inv);
        *(ushort4*)&orow[mt * 16 + 4 * g] = sv;
      }
    }
  }
}

// ---------------- proj GEMM: [87808,192] bf16 x [192,192]^T + b -> fp32 out ----------------
__global__ __launch_bounds__(256) void proj_gemm(const u16* __restrict__ ao,
                                                 const u16* __restrict__ wp_bf,
                                                 const float* __restrict__ proj_b,
                                                 float* __restrict__ out) {
  __shared__ u16 as_[64][200];
  __shared__ u16 wsx[64][200];
  const int m0 = blockIdx.x * 64;
  const u16* arow = ao + (size_t)m0 * 192;
#pragma unroll
  for (int i = 0; i < 6; ++i) {
    int idx = threadIdx.x + 256 * i;
    float4 f = ((const float4*)arow)[idx];
    *(float4*)&as_[idx / 24][(idx % 24) * 8] = f;
  }
  const int lane = threadIdx.x & 63;
  const int wv = threadIdx.x >> 6;
  const int wm = wv >> 1, wn = wv & 1;
  const int lr = lane & 15, g = lane >> 4;
  const f32x4_t zro = {0.f, 0.f, 0.f, 0.f};
  for (int cseg = 0; cseg < 3; ++cseg) {
    __syncthreads();
    const u16* wrow = wp_bf + (size_t)cseg * 64 * 192;
#pragma unroll
    for (int i = 0; i < 6; ++i) {
      int idx = threadIdx.x + 256 * i;
      float4 f = ((const float4*)wrow)[idx];
      *(float4*)&wsx[idx / 24][(idx % 24) * 8] = f;
    }
    __syncthreads();
    f32x4_t acc[2][2];
    acc[0][0] = zro; acc[0][1] = zro; acc[1][0] = zro; acc[1][1] = zro;
#pragma unroll
    for (int ks = 0; ks < 6; ++ks) {
      bf16x8_t af[2], bfr[2];
#pragma unroll
      for (int t2 = 0; t2 < 2; ++t2) {
        af[t2] = *(const bf16x8_t*)&as_[wm * 32 + t2 * 16 + lr][ks * 32 + g * 8];
        bfr[t2] = *(const bf16x8_t*)&wsx[wn * 32 + t2 * 16 + lr][ks * 32 + g * 8];
      }
#pragma unroll
      for (int mt = 0; mt < 2; ++mt)
#pragma unroll
        for (int nt = 0; nt < 2; ++nt)
          acc[mt][nt] = __builtin_amdgcn_mfma_f32_16x16x32_bf16(af[mt], bfr[nt], acc[mt][nt], 0, 0, 0);
    }
    const int c0 = cseg * 64;
#pragma unroll
    for (int mt = 0; mt < 2; ++mt) {
#pragma unroll
      for (int nt = 0; nt < 2; ++nt) {
        int gc = c0 + wn * 32 + nt * 16 + lr;
        float bias = proj_b[gc];
#pragma unroll
        for (int r = 0; r < 4; ++r) {
          int gr = m0 + wm * 32 + mt * 16 + g * 4 + r;
          out[(size_t)gr * 192 + gc] = acc[mt][nt][r] + bias;
        }
      }
    }
  }
}

extern "C" void kernel_launch(void* const* d_in, const int* in_sizes, int n_in,
                              void* d_out, int out_size, void* d_ws, size_t ws_size,
                              hipStream_t stream) {
  const float* x = (const float*)d_in[0];
  const float* mask = (const float*)d_in[1];
  const float* qkv_w = (const float*)d_in[2];
  const float* qkv_b = (const float*)d_in[3];
  const float* proj_w = (const float*)d_in[4];
  const float* proj_b = (const float*)d_in[5];
  const float* bias_table = (const float*)d_in[6];
  const int* rel_index = (const int*)d_in[7];
  float* out = (float*)d_out;
  char* ws = (char*)d_ws;

  // ws layout (bytes)
  u16* qb      = (u16*)(ws + 0);          // 33,718,272
  u16* kb      = (u16*)(ws + 33718272);   // 33,718,272
  u16* vb      = (u16*)(ws + 67436544);   // 33,718,272
  u16* ao      = (u16*)(ws + 101154816);  // 33,718,272
  u16* bias_bf = (u16*)(ws + 134873088);  // 1,449,216
  u64* mbits   = (u64*)(ws + 136322304);  // 1,053,696
  u16* wq_bf   = (u16*)(ws + 137376000);  // 221,184
  u16* wp_bf   = (u16*)(ws + 137597184);  // 73,728 -> end 137,670,912

  prep_all_k<<<8894, 256, 0, stream>>>(mask, mbits, bias_table, rel_index, bias_bf,
                                       qkv_w, proj_w, wq_bf, wp_bf);
  qkv_gemm<<<1372, 256, 0, stream>>>(x, wq_bf, qkv_b, qb, kb, vb);
  attn_k<<<1536, 512, 0, stream>>>(qb, kb, vb, bias_bf, mbits, ao);
  proj_gemm<<<1372, 256, 0, stream>>>(ao, wp_bf, proj_b, out);
}

// Round 17
// 163.863 us; speedup vs baseline: 1.3777x; 1.0248x over previous
//
#include <hip/hip_runtime.h>

typedef __bf16 bf16x8_t __attribute__((ext_vector_type(8)));
typedef float f32x4_t __attribute__((ext_vector_type(4)));
typedef short s16x4 __attribute__((ext_vector_type(4)));
typedef unsigned short u16;
typedef unsigned int u32;
typedef unsigned long long u64;

__device__ __forceinline__ u16 f2b(float f) {
  __bf16 h = (__bf16)f;
  u16 u;
  __builtin_memcpy(&u, &h, 2);
  return u;
}
__device__ __forceinline__ float u2f(u32 u) {
  float f;
  __builtin_memcpy(&f, &u, 4);
  return f;
}

union FragU { u32 u[4]; bf16x8_t v; };
union PkU { u32 u[2]; s16x4 v; };

// ============================ BASE CONFIG (R11, 167.6us, 3x-verified) ============================
// R16 change (single variable): attn_k's S-sweep and PV loops MERGED — PV accumulates
// UNNORMALIZED P·V (inv applied at write-out), so each ct's P fragment feeds PV's MFMAs
// immediately. Fills the PV accumulator-chain stall with softmax VALU within the wave
// and eliminates the 44-reg pk[22] array. Bit-identical math (same accumulation orders).
// Prior lessons (kept): R2/R12/R15 spill via reg caps; R6 occupancy tiers; R7/R8 C-from-
// global; R10 layout line-splitting; R13 K-from-L2 latency; R14 global-transpose scatter.
// =================================================================================================

// ---------------- merged prep (one launch): maskbits | bias gather | weight cvt ----------------
__global__ void prep_all_k(const float* __restrict__ mask, u64* __restrict__ mbits,
                           const float* __restrict__ bias_table,
                           const int* __restrict__ rel_index, u16* __restrict__ bias_bf,
                           const float* __restrict__ qkv_w, const float* __restrict__ proj_w,
                           u16* __restrict__ wq, u16* __restrict__ wp) {
  const int bid = blockIdx.x;
  if (bid < 5488) {
    int row = bid * 4 + (threadIdx.x >> 6);  // 0..21951
    int lane = threadIdx.x & 63;
    const float* mrow = mask + (size_t)row * 343;
#pragma unroll
    for (int it = 0; it < 6; ++it) {
      int idx = it * 64 + lane;
      float v = (idx < 343) ? mrow[idx] : -100.0f;  // pad cols masked
      u64 b = __ballot(v < -50.0f);
      if (lane == 0) mbits[(size_t)row * 6 + it] = b;
    }
  } else if (bid < 8318) {
    int i = (bid - 5488) * 256 + threadIdx.x;
    if (i >= 6 * 343 * 352) return;
    int h = i / (343 * 352);
    int rem = i - h * (343 * 352);
    int r = rem / 352;
    int c = rem - r * 352;
    u16 val = 0;
    if (c < 343) {
      int idx = rel_index[r * 343 + c];
      val = f2b(bias_table[idx * 6 + h] * 1.4426950408889634f);
    }
    bias_bf[((size_t)h * 343 + r) * 352 + c] = val;
  } else {
    int i = (bid - 8318) * 256 + threadIdx.x;
    if (i < 110592) wq[i] = f2b(qkv_w[i]);
    int j = i - 110592;
    if (j >= 0 && j < 36864) wp[j] = f2b(proj_w[j]);
  }
}

// ---------------- QKV GEMM: [87808,192] x [576,192]^T -> q,k,v bf16 [b,h,n,32] ----------------
__global__ __launch_bounds__(256) void qkv_gemm(const float* __restrict__ x,
                                                const u16* __restrict__ w_bf,
                                                const float* __restrict__ qkv_b,
                                                u16* __restrict__ qb,
                                                u16* __restrict__ kb,
                                                u16* __restrict__ vb) {
  __shared__ u16 xs[64][200];   // +8 pad
  __shared__ u16 wsx[64][200];
  const int m0 = blockIdx.x * 64;
  const float* xrow = x + (size_t)m0 * 192;
#pragma unroll
  for (int i = 0; i < 12; ++i) {
    int idx = threadIdx.x + 256 * i;
    float4 f = ((const float4*)xrow)[idx];
    int r = idx / 48, k4 = (idx % 48) * 4;
    ushort4 a;
    a.x = f2b(f.x); a.y = f2b(f.y); a.z = f2b(f.z); a.w = f2b(f.w);
    *(ushort4*)&xs[r][k4] = a;
  }
  const int lane = threadIdx.x & 63;
  const int wv = threadIdx.x >> 6;
  const int wm = wv >> 1, wn = wv & 1;
  const int lr = lane & 15, g = lane >> 4;
  // hoisted per-row offsets (gr independent of cseg): 8 divs/thread instead of 144
  int rowoff[2][4];
#pragma unroll
  for (int mt = 0; mt < 2; ++mt)
#pragma unroll
    for (int r = 0; r < 4; ++r) {
      int gr = m0 + wm * 32 + mt * 16 + g * 4 + r;
      int b_ = gr / 343;
      int n = gr - b_ * 343;
      rowoff[mt][r] = (b_ * 2058 + n) * 32;
    }
  const f32x4_t zro = {0.f, 0.f, 0.f, 0.f};
  for (int cseg = 0; cseg < 9; ++cseg) {
    __syncthreads();
    const u16* wrow = w_bf + (size_t)cseg * 64 * 192;
#pragma unroll
    for (int i = 0; i < 6; ++i) {
      int idx = threadIdx.x + 256 * i;  // 16B chunks
      float4 f = ((const float4*)wrow)[idx];
      *(float4*)&wsx[idx / 24][(idx % 24) * 8] = f;
    }
    __syncthreads();
    f32x4_t acc[2][2];
    acc[0][0] = zro; acc[0][1] = zro; acc[1][0] = zro; acc[1][1] = zro;
#pragma unroll
    for (int ks = 0; ks < 6; ++ks) {
      bf16x8_t af[2], bfr[2];
#pragma unroll
      for (int t2 = 0; t2 < 2; ++t2) {
        af[t2] = *(const bf16x8_t*)&xs[wm * 32 + t2 * 16 + lr][ks * 32 + g * 8];
        bfr[t2] = *(const bf16x8_t*)&wsx[wn * 32 + t2 * 16 + lr][ks * 32 + g * 8];
      }
#pragma unroll
      for (int mt = 0; mt < 2; ++mt)
#pragma unroll
        for (int nt = 0; nt < 2; ++nt)
          acc[mt][nt] = __builtin_amdgcn_mfma_f32_16x16x32_bf16(af[mt], bfr[nt], acc[mt][nt], 0, 0, 0);
    }
    const int c0 = cseg * 64;
    const int seg = c0 / 192;  // 0=q 1=k 2=v
    u16* dst = (seg == 0) ? qb : ((seg == 1) ? kb : vb);
    // q gets attention scale AND log2(e) folded in (exp2-based softmax downstream)
    const float scl = (seg == 0) ? (0.17677669529663687f * 1.4426950408889634f) : 1.0f;
#pragma unroll
    for (int mt = 0; mt < 2; ++mt) {
#pragma unroll
      for (int nt = 0; nt < 2; ++nt) {
        int gc = c0 + wn * 32 + nt * 16 + lr;
        float bias = qkv_b[gc];
        int c2 = gc - seg * 192;
        int hoff = (c2 >> 5) * 10976 + (c2 & 31);  // h*343*32 + d
#pragma unroll
        for (int r = 0; r < 4; ++r) {
          dst[(size_t)(rowoff[mt][r] + hoff)] = f2b((acc[mt][nt][r] + bias) * scl);
        }
      }
    }
  }
}

// ---------------- fused attention: one block per (b,h), 8 waves x 3 row-tile passes ----------------
// 512 thr / 8 waves, 3 blocks/CU; launch_bounds(512,2).
// R16: SINGLE merged ct-loop — S-tile MFMA -> exp2 -> pack -> PV MFMAs immediately
// (PV accumulates unnormalized; inv applied at write-out). ~30 VALU insts sit between
// consecutive PV accumulator MFMAs, hiding the chain + ds_read latency in-wave; the
// pk[22] register array is eliminated.
// Bias C-operand in regs from 8B bf16 pair loads; mask post-exp zeroing (exact:
// masked exp(s-100) < 4e-44 == 0 in f32). PV mfma 16x16x16: B-frag layout matches
// where swapped-QK^T leaves P -> zero shuffles.
__global__ __launch_bounds__(512, 2) void attn_k(const u16* __restrict__ qg,
                                                 const u16* __restrict__ kg,
                                                 const u16* __restrict__ vg,
                                                 const u16* __restrict__ bias_bf,
                                                 const u64* __restrict__ mbits,
                                                 u16* __restrict__ ao) {
  __shared__ u16 ksm[352][40];   // K [kc][d], +8 pad; rows 343..351 zeroed
  __shared__ u16 vtm[32][372];   // V^T [d][kc], stride 372 -> 8B frag reads 2-way (free)
  const int bh = blockIdx.x;    // 0..1535
  const int b_ = bh / 6;
  const int h = bh - b_ * 6;
  const int w = b_ & 63;
  const int t = threadIdx.x;
  const int lane = t & 63;
  const int wv = t >> 6;
  const u16* kbh = kg + (size_t)bh * 10976;
  const u16* vbh = vg + (size_t)bh * 10976;
  // stage K (343 rows x 32 d), 4 float4 per row
  for (int i = t; i < 1372; i += 512) {
    float4 f = ((const float4*)kbh)[i];
    *(float4*)&ksm[i >> 2][(i & 3) * 8] = f;
  }
  if (t < 360) ksm[343 + t / 40][t % 40] = 0;  // zero K pad rows
  // stage V transposed: each lane owns a distinct column n -> write ~2-way
#pragma unroll
  for (int k = 0; k < 3; ++k) {
    int dq = t >> 7;                   // 0..3, uniform per wave-pair
    int n = k * 128 + (t & 127);
    if (n < 343) {
      union { float4 f4; u16 s[8]; } u;
      u.f4 = ((const float4*)vbh)[n * 4 + dq];
#pragma unroll
      for (int j = 0; j < 8; ++j) vtm[dq * 8 + j][n] = u.s[j];
    }
  }
  for (int i = t; i < 928; i += 512) vtm[i / 29][343 + i % 29] = 0;  // zero V pad cols
  __syncthreads();
  const int lr = lane & 15, g = lane >> 4;
  const f32x4_t zro = {0.f, 0.f, 0.f, 0.f};
  for (int pass = 0; pass < 3; ++pass) {
    const int rt = pass * 8 + wv;  // row-tile 0..21
    if (rt >= 22) break;
    const int q0 = rt * 16;
    const int qi = q0 + lr;
    const bool qv = qi < 343;
    const int qic = qv ? qi : 342;
    FragU qfu;
    qfu.u[0] = 0u; qfu.u[1] = 0u; qfu.u[2] = 0u; qfu.u[3] = 0u;
    if (qv) qfu.v = *(const bf16x8_t*)(qg + ((size_t)bh * 343 + qi) * 32 + g * 8);
    const u16* brow = bias_bf + ((size_t)h * 343 + qic) * 352;
    const u64* mrow = mbits + ((size_t)w * 343 + qic) * 6;
    u64 mw[6];
#pragma unroll
    for (int i2 = 0; i2 < 6; ++i2) mw[i2] = mrow[i2];
    // merged sweep: bias pair-load -> C in regs -> MFMA(S+bias) -> exp2 -> mask-zero
    //               -> pack -> PV MFMAs (unnormalized accumulate) — per ct
    float sum = 0.f;
    f32x4_t oa[2] = {zro, zro};
#pragma unroll
    for (int ct = 0; ct < 22; ++ct) {
      int kjb = ct * 16 + 4 * g;
      union { uint2 u2; u32 w2[2]; } bv;
      bv.u2 = *(const uint2*)&brow[kjb];  // 8B: 4 bf16 bias values
      f32x4_t c4;
      c4[0] = u2f(bv.w2[0] << 16);
      c4[1] = u2f(bv.w2[0] & 0xFFFF0000u);
      c4[2] = u2f(bv.w2[1] << 16);
      c4[3] = u2f(bv.w2[1] & 0xFFFF0000u);
      bf16x8_t af = *(const bf16x8_t*)&ksm[ct * 16 + lr][g * 8];
      f32x4_t s4 = __builtin_amdgcn_mfma_f32_16x16x32_bf16(af, qfu.v, c4, 0, 0, 0);
      u32 bits4 = (u32)(mw[ct >> 2] >> ((ct & 3) * 16 + 4 * g)) & 0xFu;
      float p0 = ((bits4 >> 0) & 1u) ? 0.f : __builtin_amdgcn_exp2f(s4[0]);
      float p1 = ((bits4 >> 1) & 1u) ? 0.f : __builtin_amdgcn_exp2f(s4[1]);
      float p2 = ((bits4 >> 2) & 1u) ? 0.f : __builtin_amdgcn_exp2f(s4[2]);
      float p3 = ((bits4 >> 3) & 1u) ? 0.f : __builtin_amdgcn_exp2f(s4[3]);
      sum += (p0 + p1) + (p2 + p3);
      PkU pku;
      pku.u[0] = (u32)f2b(p0) | ((u32)f2b(p1) << 16);
      pku.u[1] = (u32)f2b(p2) | ((u32)f2b(p3) << 16);
      s16x4 bfrag = pku.v;
#pragma unroll
      for (int mt = 0; mt < 2; ++mt) {
        s16x4 vf = *(const s16x4*)&vtm[mt * 16 + lr][ct * 16 + g * 4];
        oa[mt] = __builtin_amdgcn_mfma_f32_16x16x16bf16_1k(vf, bfrag, oa[mt], 0, 0, 0);
      }
    }
    sum += __shfl_xor(sum, 16, 64);
    sum += __shfl_xor(sum, 32, 64);
    const float inv = 1.0f / sum;
    if (qv) {
      u16* orow = ao + ((size_t)b_ * 343 + qi) * 192 + h * 32;
#pragma unroll
      for (int mt = 0; mt < 2; ++mt) {
        ushort4 sv;
        sv.x = f2b(oa[mt][0] * inv);
        sv.y = f2b(oa[mt][1] * inv);
        sv.z = f2b(oa[mt][2] * inv);
        sv.w = f2b(oa[mt][3] * inv);
        *(ushort4*)&orow[mt * 16 + 4 * g] = sv;
      }
    }
  }
}

// ---------------- proj GEMM: [87808,192] bf16 x [192,192]^T + b -> fp32 out ----------------
__global__ __launch_bounds__(256) void proj_gemm(const u16* __restrict__ ao,
                                                 const u16* __restrict__ wp_bf,
                                                 const float* __restrict__ proj_b,
                                                 float* __restrict__ out) {
  __shared__ u16 as_[64][200];
  __shared__ u16 wsx[64][200];
  const int m0 = blockIdx.x * 64;
  const u16* arow = ao + (size_t)m0 * 192;
#pragma unroll
  for (int i = 0; i < 6; ++i) {
    int idx = threadIdx.x + 256 * i;
    float4 f = ((const float4*)arow)[idx];
    *(float4*)&as_[idx / 24][(idx % 24) * 8] = f;
  }
  const int lane = threadIdx.x & 63;
  const int wv = threadIdx.x >> 6;
  const int wm = wv >> 1, wn = wv & 1;
  const int lr = lane & 15, g = lane >> 4;
  const f32x4_t zro = {0.f, 0.f, 0.f, 0.f};
  for (int cseg = 0; cseg < 3; ++cseg) {
    __syncthreads();
    const u16* wrow = wp_bf + (size_t)cseg * 64 * 192;
#pragma unroll
    for (int i = 0; i < 6; ++i) {
      int idx = threadIdx.x + 256 * i;
      float4 f = ((const float4*)wrow)[idx];
      *(float4*)&wsx[idx / 24][(idx % 24) * 8] = f;
    }
    __syncthreads();
    f32x4_t acc[2][2];
    acc[0][0] = zro; acc[0][1] = zro; acc[1][0] = zro; acc[1][1] = zro;
#pragma unroll
    for (int ks = 0; ks < 6; ++ks) {
      bf16x8_t af[2], bfr[2];
#pragma unroll
      for (int t2 = 0; t2 < 2; ++t2) {
        af[t2] = *(const bf16x8_t*)&as_[wm * 32 + t2 * 16 + lr][ks * 32 + g * 8];
        bfr[t2] = *(const bf16x8_t*)&wsx[wn * 32 + t2 * 16 + lr][ks * 32 + g * 8];
      }
#pragma unroll
      for (int mt = 0; mt < 2; ++mt)
#pragma unroll
        for (int nt = 0; nt < 2; ++nt)
          acc[mt][nt] = __builtin_amdgcn_mfma_f32_16x16x32_bf16(af[mt], bfr[nt], acc[mt][nt], 0, 0, 0);
    }
    const int c0 = cseg * 64;
#pragma unroll
    for (int mt = 0; mt < 2; ++mt) {
#pragma unroll
      for (int nt = 0; nt < 2; ++nt) {
        int gc = c0 + wn * 32 + nt * 16 + lr;
        float bias = proj_b[gc];
#pragma unroll
        for (int r = 0; r < 4; ++r) {
          int gr = m0 + wm * 32 + mt * 16 + g * 4 + r;
          out[(size_t)gr * 192 + gc] = acc[mt][nt][r] + bias;
        }
      }
    }
  }
}

extern "C" void kernel_launch(void* const* d_in, const int* in_sizes, int n_in,
                              void* d_out, int out_size, void* d_ws, size_t ws_size,
                              hipStream_t stream) {
  const float* x = (const float*)d_in[0];
  const float* mask = (const float*)d_in[1];
  const float* qkv_w = (const float*)d_in[2];
  const float* qkv_b = (const float*)d_in[3];
  const float* proj_w = (const float*)d_in[4];
  const float* proj_b = (const float*)d_in[5];
  const float* bias_table = (const float*)d_in[6];
  const int* rel_index = (const int*)d_in[7];
  float* out = (float*)d_out;
  char* ws = (char*)d_ws;

  // ws layout (bytes)
  u16* qb      = (u16*)(ws + 0);          // 33,718,272
  u16* kb      = (u16*)(ws + 33718272);   // 33,718,272
  u16* vb      = (u16*)(ws + 67436544);   // 33,718,272
  u16* ao      = (u16*)(ws + 101154816);  // 33,718,272
  u16* bias_bf = (u16*)(ws + 134873088);  // 1,449,216
  u64* mbits   = (u64*)(ws + 136322304);  // 1,053,696
  u16* wq_bf   = (u16*)(ws + 137376000);  // 221,184
  u16* wp_bf   = (u16*)(ws + 137597184);  // 73,728 -> end 137,670,912

  prep_all_k<<<8894, 256, 0, stream>>>(mask, mbits, bias_table, rel_index, bias_bf,
                                       qkv_w, proj_w, wq_bf, wp_bf);
  qkv_gemm<<<1372, 256, 0, stream>>>(x, wq_bf, qkv_b, qb, kb, vb);
  attn_k<<<1536, 512, 0, stream>>>(qb, kb, vb, bias_bf, mbits, ao);
  proj_gemm<<<1372, 256, 0, stream>>>(ao, wp_bf, proj_b, out);
}